// Round 3
// baseline (115.404 us; speedup 1.0000x reference)
//
#include <hip/hip_runtime.h>

#define NB    256
#define DIN   128
#define HH    512
#define RANK  8
#define SCALE 2.0f
#define LN2   0.69314718f
#define C192  5.2083335e-3f   // 1/192, same constant as sp_poly

// ---- workspace layout (float offsets) ----
#define WS_ACC   0                    // [2 khalf][256 b][512 h][12]  (11 used)
#define WS_B     3145728              // [2 layer][256 b][9 vec][512 k]
#define WS_XPRE  5505024              // [2 layer][256 b][512 h]
#define WS_SCAL  5767168              // [2 layer][256 b][80]  (0=Z0, 1..8=u, 16..79=M[r*8+s])
#define WS_END   5808128

typedef float v2f __attribute__((ext_vector_type(2)));

__device__ __forceinline__ v2f mk2(float a, float b) { v2f r; r.x = a; r.y = b; return r; }

__device__ __forceinline__ v2f pk_fma(v2f a, v2f b, v2f c) {
    v2f d; asm("v_pk_fma_f32 %0, %1, %2, %3" : "=v"(d) : "v"(a), "v"(b), "v"(c)); return d;
}
__device__ __forceinline__ v2f pk_mul(v2f a, v2f b) {
    v2f d; asm("v_pk_mul_f32 %0, %1, %2" : "=v"(d) : "v"(a), "v"(b)); return d;
}
__device__ __forceinline__ v2f pk_fma_blo(v2f a, v2f b, v2f c) {
    v2f d; asm("v_pk_fma_f32 %0, %1, %2, %3 op_sel:[0,0,0] op_sel_hi:[1,0,1]"
               : "=v"(d) : "v"(a), "v"(b), "v"(c)); return d;
}
__device__ __forceinline__ v2f pk_fma_bhi(v2f a, v2f b, v2f c) {
    v2f d; asm("v_pk_fma_f32 %0, %1, %2, %3 op_sel:[0,1,0] op_sel_hi:[1,1,1]"
               : "=v"(d) : "v"(a), "v"(b), "v"(c)); return d;
}

__device__ __forceinline__ float sp_stable(float v) {
    float e = __expf(-fabsf(v));
    return fmaxf(v, 0.0f) + __logf(1.0f + e);
}
__device__ __forceinline__ float sp_poly(float v) {
    float u = v * v;
    float t = fmaf(u, -C192, 0.125f);
    t = fmaf(u, t, LN2);
    return fmaf(v, 0.5f, t);
}

#define DPP_ADD(x, ctrl, rm, bm, bc)                                            \
    (x) = (x) + __int_as_float(__builtin_amdgcn_update_dpp(                     \
              0, __float_as_int(x), (ctrl), (rm), (bm), (bc)))

__device__ __forceinline__ float wave_sum64(float x) {
    DPP_ADD(x, 0x111, 0xf, 0xf, true);
    DPP_ADD(x, 0x112, 0xf, 0xf, true);
    DPP_ADD(x, 0x114, 0xf, 0xf, true);
    DPP_ADD(x, 0x118, 0xf, 0xf, true);
    DPP_ADD(x, 0x142, 0xa, 0xf, false);
    DPP_ADD(x, 0x143, 0xc, 0xf, false);
    return x;
}

// ------------------------------------------------------------------
// Shared: build B-vectors (c, y_r = c*az_r) and scalars (Z0, u_r, M_rs)
// for layer `ell` from activations in z_s. Call from all threads.
// ------------------------------------------------------------------
__device__ void build_b_scal(int b, int ell, const float* __restrict__ Az,
                             float* __restrict__ ws, const float* __restrict__ z_s,
                             float* __restrict__ y_s, float* __restrict__ az_s,
                             float* __restrict__ wred)
{
    const int tid = threadIdx.x;
    float* wsB = ws + WS_B + (ell * 256 + b) * (9 * HH);
    float* wsS = ws + WS_SCAL + (ell * 256 + b) * 80;
    __syncthreads();   // z_s ready
    if (tid < 512) {
        const int k = tid, w = tid >> 6;
        float c = z_s[k];
        wsB[k] = c;
        float ys[RANK];
        #pragma unroll
        for (int r = 0; r < RANK; ++r) {
            float az = Az[(b * RANK + r) * HH + k];
            az_s[r * HH + k] = az;
            float y = c * az;
            y_s[r * HH + k] = y;
            wsB[(1 + r) * HH + k] = y;
            ys[r] = y;
        }
        float zp = wave_sum64(c);
        if ((tid & 63) == 63) wred[w * 12 + 0] = zp;
        #pragma unroll
        for (int r = 0; r < RANK; ++r) {
            float up = wave_sum64(ys[r]);
            if ((tid & 63) == 63) wred[w * 12 + 1 + r] = up;
        }
    }
    __syncthreads();
    if (tid < 9) {
        float s = 0.f;
        #pragma unroll
        for (int w = 0; w < 8; ++w) s += wred[w * 12 + tid];
        wsS[tid] = s;
    }
    if (tid < 512) {
        const int p = tid >> 3, li = tid & 7;
        const int r = p >> 3, s2 = p & 7;
        float m = 0.f;
        #pragma unroll 8
        for (int j = 0; j < 64; ++j) {
            int k = li + 8 * j;
            m += y_s[r * HH + k] * az_s[s2 * HH + k];
        }
        m += __shfl_down(m, 4, 8);
        m += __shfl_down(m, 2, 8);
        m += __shfl_down(m, 1, 8);
        if (li == 0) wsS[16 + p] = m;
    }
}

// ------------------------------------------------------------------
// K0: per-sample prologue: tx, xpre0/1/2, z0, B1 vectors + scalars.
// ------------------------------------------------------------------
__global__ __launch_bounds__(1024, 4) void kprep(
    const float* __restrict__ x,
    const float* __restrict__ Wx0, const float* __restrict__ b0,
    const float* __restrict__ Ax0, const float* __restrict__ Bx0, const float* __restrict__ bd0,
    const float* __restrict__ Wx1, const float* __restrict__ b1,
    const float* __restrict__ Ax1, const float* __restrict__ Bx1, const float* __restrict__ bd1,
    const float* __restrict__ Wx2, const float* __restrict__ b2,
    const float* __restrict__ Ax2, const float* __restrict__ Bx2, const float* __restrict__ bd2,
    const float* __restrict__ Az1, float* __restrict__ ws)
{
    const int b = blockIdx.x, tid = threadIdx.x;
    __shared__ float x_s[DIN];
    __shared__ float tx_s[3][RANK];
    __shared__ float xpre0_s[HH];
    __shared__ float z_s[HH];
    __shared__ float y_s[RANK * HH];
    __shared__ float az_s[RANK * HH];
    __shared__ float wred[96];

    if (tid < DIN) x_s[tid] = x[b * DIN + tid];
    __syncthreads();

    if (tid < 384) {
        const int g = tid >> 7, t = tid & 127;
        const int r = t >> 4, l = t & 15;
        const float* A  = (g == 0) ? Ax0 : (g == 1) ? Ax1 : Ax2;
        const float* Ab = A + (b * RANK + r) * DIN;
        float s = 0.f;
        #pragma unroll
        for (int k = 0; k < 8; ++k) { int d = l + 16 * k; s += Ab[d] * x_s[d]; }
        s += __shfl_down(s, 8, 16);
        s += __shfl_down(s, 4, 16);
        s += __shfl_down(s, 2, 16);
        s += __shfl_down(s, 1, 16);
        if (l == 0) tx_s[g][r] = s;
    }
    __syncthreads();

    #pragma unroll 1
    for (int idx = tid; idx < 3 * HH; idx += 1024) {
        const int l = idx >> 9;
        const int h = idx & (HH - 1);
        const float* Wxl = (l == 0) ? Wx0 : (l == 1) ? Wx1 : Wx2;
        const float* bl  = (l == 0) ? b0  : (l == 1) ? b1  : b2;
        const float* Bxl = (l == 0) ? Bx0 : (l == 1) ? Bx1 : Bx2;
        const float* bdl = (l == 0) ? bd0 : (l == 1) ? bd1 : bd2;
        const float4* wrow = reinterpret_cast<const float4*>(Wxl + h * DIN);
        float s = 0.f;
        #pragma unroll 8
        for (int q = 0; q < DIN / 4; ++q) {
            float4 w = wrow[q];
            const float* xs = &x_s[q * 4];
            s += w.x * xs[0] + w.y * xs[1] + w.z * xs[2] + w.w * xs[3];
        }
        const float* bxr = Bxl + (b * HH + h) * RANK;
        float t = 0.f;
        #pragma unroll
        for (int r = 0; r < RANK; ++r) t += bxr[r] * tx_s[l][r];
        float v = s + SCALE * t + bl[h] + bdl[b * HH + h];
        if (l == 0) xpre0_s[h] = v;
        else        ws[WS_XPRE + ((l - 1) * 256 + b) * HH + h] = v;
    }
    __syncthreads();

    if (tid < 512) z_s[tid] = sp_stable(xpre0_s[tid]);
    build_b_scal(b, 0, Az1, ws, z_s, y_s, az_s, wred);
}

// ------------------------------------------------------------------
// Kz: batched 3-matrix GEMM: P=W*c, R_r=W*y_r, Q2=W^2*c, Q4=W^4*c.
// block = 64 rows x 16 samples x K-half(256). 512 threads, tile 2r x 1s.
// ------------------------------------------------------------------
__global__ __launch_bounds__(512, 2) void kz(
    const float* __restrict__ W, const float* __restrict__ Bv,
    float* __restrict__ acco)
{
    const int bid = blockIdx.x;
    const int rg = bid & 7, sg = (bid >> 3) & 15, kh = bid >> 7;
    const int t = threadIdx.x;
    const int rp = t >> 4;        // 0..31 row-pair
    const int sl = t & 15;        // sample slot

    __shared__ float As[3][64][68];
    __shared__ float Bs[16][9][68];

    v2f acc[2][11];
    #pragma unroll
    for (int r2 = 0; r2 < 2; ++r2)
        #pragma unroll
        for (int j = 0; j < 11; ++j) acc[r2][j] = mk2(0.f, 0.f);

    const float* Wbase  = W  + (rg * 64) * HH + kh * 256;
    const float* Bvbase = Bv + (sg * 16) * (9 * HH) + kh * 256;

    #pragma unroll 1
    for (int ks = 0; ks < 4; ++ks) {
        const int kb = ks * 64;
        __syncthreads();
        // stage A tile (64r x 64k) + derived squares/quads
        #pragma unroll
        for (int e0 = 0; e0 < 2; ++e0) {
            const int e = t + e0 * 512;
            const int row = e >> 4, kq = e & 15;
            float4 w = *reinterpret_cast<const float4*>(Wbase + row * HH + kb + 4 * kq);
            float4 s, q;
            s.x = w.x * w.x; s.y = w.y * w.y; s.z = w.z * w.z; s.w = w.w * w.w;
            q.x = s.x * s.x; q.y = s.y * s.y; q.z = s.z * s.z; q.w = s.w * s.w;
            *reinterpret_cast<float4*>(&As[0][row][4 * kq]) = w;
            *reinterpret_cast<float4*>(&As[1][row][4 * kq]) = s;
            *reinterpret_cast<float4*>(&As[2][row][4 * kq]) = q;
        }
        // stage B tile (16s x 9v x 64k)
        #pragma unroll 1
        for (int e = t; e < 2304; e += 512) {
            const int p = e >> 4, kq = e & 15;
            const int s = p / 9, v = p - 9 * s;
            float4 bb = *reinterpret_cast<const float4*>(Bvbase + (s * 9 + v) * HH + kb + 4 * kq);
            *reinterpret_cast<float4*>(&Bs[s][v][4 * kq]) = bb;
        }
        __syncthreads();
        #pragma unroll
        for (int k4 = 0; k4 < 16; ++k4) {
            const int kl = 4 * k4;
            v2f bv[9][2];
            #pragma unroll
            for (int v = 0; v < 9; ++v) {
                float4 f = *reinterpret_cast<const float4*>(&Bs[sl][v][kl]);
                bv[v][0] = mk2(f.x, f.y); bv[v][1] = mk2(f.z, f.w);
            }
            #pragma unroll
            for (int r2 = 0; r2 < 2; ++r2) {
                float4 fw = *reinterpret_cast<const float4*>(&As[0][2 * rp + r2][kl]);
                float4 fs = *reinterpret_cast<const float4*>(&As[1][2 * rp + r2][kl]);
                float4 fq = *reinterpret_cast<const float4*>(&As[2][2 * rp + r2][kl]);
                v2f w0 = mk2(fw.x, fw.y), w1 = mk2(fw.z, fw.w);
                v2f s0 = mk2(fs.x, fs.y), s1 = mk2(fs.z, fs.w);
                v2f q0 = mk2(fq.x, fq.y), q1 = mk2(fq.z, fq.w);
                acc[r2][0] = pk_fma(w0, bv[0][0], acc[r2][0]);
                acc[r2][0] = pk_fma(w1, bv[0][1], acc[r2][0]);
                #pragma unroll
                for (int r = 0; r < 8; ++r) {
                    acc[r2][1 + r] = pk_fma(w0, bv[1 + r][0], acc[r2][1 + r]);
                    acc[r2][1 + r] = pk_fma(w1, bv[1 + r][1], acc[r2][1 + r]);
                }
                acc[r2][9]  = pk_fma(s0, bv[0][0], acc[r2][9]);
                acc[r2][9]  = pk_fma(s1, bv[0][1], acc[r2][9]);
                acc[r2][10] = pk_fma(q0, bv[0][0], acc[r2][10]);
                acc[r2][10] = pk_fma(q1, bv[0][1], acc[r2][10]);
            }
        }
    }
    const int samp = sg * 16 + sl;
    #pragma unroll
    for (int r2 = 0; r2 < 2; ++r2) {
        const int h = rg * 64 + 2 * rp + r2;
        float* o = acco + ((size_t)((kh * 256 + samp) * HH + h)) * 12;
        float r[11];
        #pragma unroll
        for (int j = 0; j < 11; ++j) r[j] = acc[r2][j].x + acc[r2][j].y;
        *reinterpret_cast<float4*>(o)     = make_float4(r[0], r[1], r[2], r[3]);
        *reinterpret_cast<float4*>(o + 4) = make_float4(r[4], r[5], r[6], r[7]);
        o[8] = r[8]; o[9] = r[9]; o[10] = r[10];
    }
}

// ------------------------------------------------------------------
// Kmid: merge layer-1 accs -> z1; build B2 vectors + layer-2 scalars.
// ------------------------------------------------------------------
__global__ __launch_bounds__(1024, 4) void kmid(
    const float* __restrict__ Az2, const float* __restrict__ Bz1,
    float* __restrict__ ws)
{
    const int b = blockIdx.x, tid = threadIdx.x;
    __shared__ float z_s[HH];
    __shared__ float sc_s[80];
    __shared__ float y_s[RANK * HH];
    __shared__ float az_s[RANK * HH];
    __shared__ float wred[96];

    if (tid < 80) sc_s[tid] = ws[WS_SCAL + b * 80 + tid];
    __syncthreads();
    if (tid < 512) {
        const int h = tid;
        const float* a0 = ws + WS_ACC + ((size_t)((0 * 256 + b) * HH + h)) * 12;
        const float* a1 = ws + WS_ACC + ((size_t)((1 * 256 + b) * HH + h)) * 12;
        float P  = a0[0] + a1[0];
        float Q2 = a0[9] + a1[9];
        float Q4 = a0[10] + a1[10];
        const float* bz = Bz1 + (b * HH + h) * RANK;
        float uDot = 0.f, RDot = 0.f, quad = 0.f;
        #pragma unroll
        for (int r = 0; r < RANK; ++r) {
            float br = bz[r];
            uDot = fmaf(br, sc_s[1 + r], uDot);
            RDot = fmaf(br, a0[1 + r] + a1[1 + r], RDot);
            float mr = 0.f;
            #pragma unroll
            for (int s = 0; s < RANK; ++s) mr = fmaf(sc_s[16 + r * 8 + s], bz[s], mr);
            quad = fmaf(br, mr, quad);
        }
        float pre = ws[WS_XPRE + (0 * 256 + b) * HH + h]
                  + LN2 * sc_s[0] + 0.5f * P + uDot
                  + 0.125f * Q2 + 0.5f * RDot + 0.5f * quad - Q4 * C192;
        z_s[h] = sp_stable(pre);
    }
    build_b_scal(b, 1, Az2, ws, z_s, y_s, az_s, wred);
}

// ------------------------------------------------------------------
// Kout: merge layer-2 accs -> z2; output layer; reduce to out[b].
// ------------------------------------------------------------------
__global__ __launch_bounds__(512, 2) void kout(
    const float* __restrict__ x,
    const float* __restrict__ oWx, const float* __restrict__ ob,
    const float* __restrict__ oAx, const float* __restrict__ oBx, const float* __restrict__ obd,
    const float* __restrict__ oWz, const float* __restrict__ oAz, const float* __restrict__ oBz,
    const float* __restrict__ Bz2, float* __restrict__ ws, float* __restrict__ out)
{
    const int b = blockIdx.x, tid = threadIdx.x;
    __shared__ float x_s[DIN];
    __shared__ float sc_s[80];
    __shared__ float red_s[HH];
    __shared__ float tx_s[RANK];

    if (tid < DIN) x_s[tid] = x[b * DIN + tid];
    if (tid < 80) sc_s[tid] = ws[WS_SCAL + (256 + b) * 80 + tid];
    __syncthreads();

    float partial;
    {
        const int h = tid;
        const float* a0 = ws + WS_ACC + ((size_t)((0 * 256 + b) * HH + h)) * 12;
        const float* a1 = ws + WS_ACC + ((size_t)((1 * 256 + b) * HH + h)) * 12;
        float P  = a0[0] + a1[0];
        float Q2 = a0[9] + a1[9];
        float Q4 = a0[10] + a1[10];
        const float* bz = Bz2 + (b * HH + h) * RANK;
        float uDot = 0.f, RDot = 0.f, quad = 0.f;
        #pragma unroll
        for (int r = 0; r < RANK; ++r) {
            float br = bz[r];
            uDot = fmaf(br, sc_s[1 + r], uDot);
            RDot = fmaf(br, a0[1 + r] + a1[1 + r], RDot);
            float mr = 0.f;
            #pragma unroll
            for (int s = 0; s < RANK; ++s) mr = fmaf(sc_s[16 + r * 8 + s], bz[s], mr);
            quad = fmaf(br, mr, quad);
        }
        float pre = ws[WS_XPRE + (1 * 256 + b) * HH + h]
                  + LN2 * sc_s[0] + 0.5f * P + uDot
                  + 0.125f * Q2 + 0.5f * RDot + 0.5f * quad - Q4 * C192;
        float z2 = sp_stable(pre);
        float d = 0.f;
        #pragma unroll
        for (int r = 0; r < RANK; ++r)
            d = fmaf(oBz[b * RANK + r], oAz[(b * RANK + r) * HH + h], d);
        partial = z2 * sp_poly(fmaf(SCALE, d, oWz[h]));
        if (tid < DIN) partial += oWx[tid] * x_s[tid];
    }
    red_s[tid] = partial;
    __syncthreads();

    if (tid < 128) {
        const int r = tid >> 4, l = tid & 15;
        const float* Ab = oAx + (b * RANK + r) * DIN;
        float s = 0.f;
        #pragma unroll
        for (int k = 0; k < 8; ++k) { int d = l + 16 * k; s += Ab[d] * x_s[d]; }
        s += __shfl_down(s, 8, 16);
        s += __shfl_down(s, 4, 16);
        s += __shfl_down(s, 2, 16);
        s += __shfl_down(s, 1, 16);
        if (l == 0) tx_s[r] = s;
    }
    __syncthreads();
    for (int s = 256; s > 0; s >>= 1) {
        if (tid < s) red_s[tid] += red_s[tid + s];
        __syncthreads();
    }
    if (tid == 0) {
        float t2 = 0.f;
        #pragma unroll
        for (int r = 0; r < RANK; ++r) t2 = fmaf(oBx[b * RANK + r], tx_s[r], t2);
        out[b] = red_s[0] + ob[0] + obd[b] + SCALE * t2;
    }
}

// ==================================================================
// Fallback single-kernel path (round-2 kernel) if ws too small.
// ==================================================================
__global__ __launch_bounds__(1024, 4) void lora_fused(
    const float* __restrict__ x,
    const float* __restrict__ Wx0, const float* __restrict__ b0,
    const float* __restrict__ Ax0, const float* __restrict__ Bx0, const float* __restrict__ bd0,
    const float* __restrict__ Wx1, const float* __restrict__ b1,
    const float* __restrict__ Ax1, const float* __restrict__ Bx1, const float* __restrict__ bd1,
    const float* __restrict__ Wx2, const float* __restrict__ b2,
    const float* __restrict__ Ax2, const float* __restrict__ Bx2, const float* __restrict__ bd2,
    const float* __restrict__ Wz1, const float* __restrict__ Az1, const float* __restrict__ Bz1,
    const float* __restrict__ Wz2, const float* __restrict__ Az2, const float* __restrict__ Bz2,
    const float* __restrict__ oWx, const float* __restrict__ ob,
    const float* __restrict__ oAx, const float* __restrict__ oBx, const float* __restrict__ obd,
    const float* __restrict__ oWz, const float* __restrict__ oAz, const float* __restrict__ oBz,
    float* __restrict__ out)
{
    const int b    = blockIdx.x;
    const int tid  = threadIdx.x;
    const int lane = tid & 63;
    const int wid  = tid >> 6;
    const int rg   = wid >> 1;
    const int ch   = wid & 1;
    const bool odd = lane & 1;

    __shared__ float x_s[DIN];
    __shared__ float z_s[HH];
    __shared__ float tx_s[4][RANK];
    __shared__ float xpre_s[3][HH];
    __shared__ float red4_s[4][2][HH + 2];
    __shared__ __attribute__((aligned(16))) float Az_s[2][RANK * HH];
    __shared__ __attribute__((aligned(16))) float Bz_s[2][HH * RANK];
    __shared__ float red8[16];

    const v2f cA2 = mk2(-C192, -C192);
    const v2f cB2 = mk2(0.125f, 0.125f);
    const v2f cL2 = mk2(LN2, LN2);
    const v2f cH2 = mk2(0.5f, 0.5f);

    if (tid < DIN) x_s[tid] = x[b * DIN + tid];
    {
        const float4* a1 = reinterpret_cast<const float4*>(Az1 + b * RANK * HH);
        const float4* a2 = reinterpret_cast<const float4*>(Az2 + b * RANK * HH);
        const float4* z1 = reinterpret_cast<const float4*>(Bz1 + b * HH * RANK);
        const float4* z2 = reinterpret_cast<const float4*>(Bz2 + b * HH * RANK);
        reinterpret_cast<float4*>(Az_s[0])[tid] = a1[tid];
        reinterpret_cast<float4*>(Az_s[1])[tid] = a2[tid];
        reinterpret_cast<float4*>(Bz_s[0])[tid] = z1[tid];
        reinterpret_cast<float4*>(Bz_s[1])[tid] = z2[tid];
    }
    __syncthreads();

    if (tid < 512) {
        const int g = tid >> 7;
        const int t = tid & 127;
        const int r = t >> 4, l = t & 15;
        const float* A  = (g == 0) ? Ax0 : (g == 1) ? Ax1 : (g == 2) ? Ax2 : oAx;
        const float* Ab = A + (b * RANK + r) * DIN;
        float s = 0.f;
        #pragma unroll
        for (int k = 0; k < 8; ++k) { int d = l + 16 * k; s += Ab[d] * x_s[d]; }
        s += __shfl_down(s, 8, 16);
        s += __shfl_down(s, 4, 16);
        s += __shfl_down(s, 2, 16);
        s += __shfl_down(s, 1, 16);
        if (l == 0) tx_s[g][r] = s;
    }
    __syncthreads();

    #pragma unroll 1
    for (int idx = tid; idx < 3 * HH; idx += 1024) {
        const int l = idx >> 9;
        const int h = idx & (HH - 1);
        const float* Wxl = (l == 0) ? Wx0 : (l == 1) ? Wx1 : Wx2;
        const float* bl  = (l == 0) ? b0  : (l == 1) ? b1  : b2;
        const float* Bxl = (l == 0) ? Bx0 : (l == 1) ? Bx1 : Bx2;
        const float* bdl = (l == 0) ? bd0 : (l == 1) ? bd1 : bd2;
        const float4* wrow = reinterpret_cast<const float4*>(Wxl + h * DIN);
        float s = 0.f;
        #pragma unroll 8
        for (int q = 0; q < DIN / 4; ++q) {
            float4 w = wrow[q];
            const float* xs = &x_s[q * 4];
            s += w.x * xs[0] + w.y * xs[1] + w.z * xs[2] + w.w * xs[3];
        }
        const float* bxr = Bxl + (b * HH + h) * RANK;
        float t = 0.f;
        #pragma unroll
        for (int r = 0; r < RANK; ++r) t += bxr[r] * tx_s[l][r];
        xpre_s[l][h] = s + SCALE * t + bl[h] + bdl[b * HH + h];
    }
    __syncthreads();

    if (tid < HH) z_s[tid] = sp_stable(xpre_s[0][tid]);
    __syncthreads();

    auto zlayer = [&](const float* __restrict__ Wz, int li) {
        const int c0 = ch * 256 + (lane << 2);
        v2f zk2[2], az[RANK][2];
        {
            float4 zz = *reinterpret_cast<const float4*>(&z_s[c0]);
            zk2[0] = mk2(zz.x, zz.y); zk2[1] = mk2(zz.z, zz.w);
        }
        #pragma unroll
        for (int r = 0; r < RANK; ++r) {
            float4 a4 = *reinterpret_cast<const float4*>(&Az_s[li][r * HH + c0]);
            az[r][0] = mk2(SCALE * a4.x, SCALE * a4.y);
            az[r][1] = mk2(SCALE * a4.z, SCALE * a4.w);
        }
        const float* wp = Wz + (rg * 64) * HH + c0;
        const float* bp = &Bz_s[li][(rg * 64) * RANK];
        float* rp = &red4_s[lane >> 4][ch][rg * 64 + (lane & 1)];

        v2f wA[2], wB[2], bzA[4], bzB[4];
        auto loadw = [&](v2f* dst, int row) {
            float4 w4 = *reinterpret_cast<const float4*>(wp + row * HH);
            dst[0] = mk2(w4.x, w4.y); dst[1] = mk2(w4.z, w4.w);
        };
        auto loadb = [&](v2f* dst, int row) {
            const float4* q = reinterpret_cast<const float4*>(bp + row * RANK);
            float4 q0 = q[0], q1 = q[1];
            dst[0] = mk2(q0.x, q0.y); dst[1] = mk2(q0.z, q0.w);
            dst[2] = mk2(q1.x, q1.y); dst[3] = mk2(q1.z, q1.w);
        };
        auto rowsum = [&](const v2f* wz, const v2f* bz) -> float {
            v2f s = mk2(0.f, 0.f);
            #pragma unroll
            for (int g = 0; g < 2; ++g) {
                v2f d = wz[g];
                d = pk_fma_blo(az[0][g], bz[0], d);
                d = pk_fma_bhi(az[1][g], bz[0], d);
                d = pk_fma_blo(az[2][g], bz[1], d);
                d = pk_fma_bhi(az[3][g], bz[1], d);
                d = pk_fma_blo(az[4][g], bz[2], d);
                d = pk_fma_bhi(az[5][g], bz[2], d);
                d = pk_fma_blo(az[6][g], bz[3], d);
                d = pk_fma_bhi(az[7][g], bz[3], d);
                v2f u = pk_mul(d, d);
                v2f t = pk_fma(u, cA2, cB2);
                t = pk_fma(u, t, cL2);
                t = pk_fma(d, cH2, t);
                s = pk_fma(zk2[g], t, s);
            }
            return s.x + s.y;
        };

        loadw(wA, 0); loadb(bzA, 0);
        #pragma unroll 1
        for (int hs = 0; hs < 64; hs += 2) {
            loadw(wB, hs + 1); loadb(bzB, hs + 1);
            float sA = rowsum(wA, bzA);
            const int hn = (hs + 2) & 63;
            loadw(wA, hn); loadb(bzA, hn);
            float sB = rowsum(wB, bzB);
            float m = odd ? sB : sA;
            float o = odd ? sA : sB;
            m = m + __int_as_float(__builtin_amdgcn_update_dpp(
                    0, __float_as_int(o), 0xB1, 0xf, 0xf, true));
            DPP_ADD(m, 0x112, 0xf, 0xf, true);
            DPP_ADD(m, 0x114, 0xf, 0xf, true);
            DPP_ADD(m, 0x118, 0xf, 0xf, true);
            if ((lane & 14) == 14) rp[hs] = m;
        }
    };

    zlayer(Wz1, 0);
    __syncthreads();
    if (tid < HH) {
        float acc = xpre_s[1][tid];
        #pragma unroll
        for (int q = 0; q < 4; ++q) acc += red4_s[q][0][tid] + red4_s[q][1][tid];
        z_s[tid] = sp_stable(acc);
    }
    __syncthreads();

    zlayer(Wz2, 1);
    __syncthreads();
    if (tid < HH) {
        float acc = xpre_s[2][tid];
        #pragma unroll
        for (int q = 0; q < 4; ++q) acc += red4_s[q][0][tid] + red4_s[q][1][tid];
        z_s[tid] = sp_stable(acc);
    }
    __syncthreads();

    {
        float partial = 0.f;
        if (tid < HH) {
            const float* oBzb = oBz + b * RANK;
            const float* oAzb = oAz + b * RANK * HH;
            float d = 0.f;
            #pragma unroll
            for (int r = 0; r < RANK; ++r) d = fmaf(oBzb[r], oAzb[r * HH + tid], d);
            partial = z_s[tid] * sp_poly(fmaf(SCALE, d, oWz[tid]));
            if (tid < DIN) partial += oWx[tid] * x_s[tid];
        }
        partial = wave_sum64(partial);
        if (lane == 63) red8[wid] = partial;
        __syncthreads();
        if (tid == 0) {
            float t = 0.f;
            #pragma unroll
            for (int w = 0; w < 8; ++w) t += red8[w];
            float t2 = 0.f;
            const float* oBxb = oBx + b * RANK;
            #pragma unroll
            for (int r = 0; r < RANK; ++r) t2 = fmaf(oBxb[r], tx_s[3][r], t2);
            out[b] = t + ob[0] + obd[b] + SCALE * t2;
        }
    }
}

extern "C" void kernel_launch(void* const* d_in, const int* in_sizes, int n_in,
                              void* d_out, int out_size, void* d_ws, size_t ws_size,
                              hipStream_t stream) {
    const float* x   = (const float*)d_in[0];
    const float* Wx0 = (const float*)d_in[1];
    const float* b0  = (const float*)d_in[2];
    const float* Ax0 = (const float*)d_in[3];
    const float* Bx0 = (const float*)d_in[4];
    const float* bd0 = (const float*)d_in[5];
    const float* Wx1 = (const float*)d_in[6];
    const float* b1  = (const float*)d_in[7];
    const float* Ax1 = (const float*)d_in[8];
    const float* Bx1 = (const float*)d_in[9];
    const float* bd1 = (const float*)d_in[10];
    const float* Wx2 = (const float*)d_in[11];
    const float* b2  = (const float*)d_in[12];
    const float* Ax2 = (const float*)d_in[13];
    const float* Bx2 = (const float*)d_in[14];
    const float* bd2 = (const float*)d_in[15];
    const float* Wz1 = (const float*)d_in[16];
    const float* Az1 = (const float*)d_in[17];
    const float* Bz1 = (const float*)d_in[18];
    const float* Wz2 = (const float*)d_in[19];
    const float* Az2 = (const float*)d_in[20];
    const float* Bz2 = (const float*)d_in[21];
    const float* oWx = (const float*)d_in[22];
    const float* ob  = (const float*)d_in[23];
    const float* oAx = (const float*)d_in[24];
    const float* oBx = (const float*)d_in[25];
    const float* obd = (const float*)d_in[26];
    const float* oWz = (const float*)d_in[27];
    const float* oAz = (const float*)d_in[28];
    const float* oBz = (const float*)d_in[29];
    float* out = (float*)d_out;

    if (ws_size >= (size_t)WS_END * sizeof(float) && d_ws != nullptr) {
        float* ws = (float*)d_ws;
        kprep<<<NB, 1024, 0, stream>>>(x, Wx0, b0, Ax0, Bx0, bd0,
                                       Wx1, b1, Ax1, Bx1, bd1,
                                       Wx2, b2, Ax2, Bx2, bd2, Az1, ws);
        kz<<<NB, 512, 0, stream>>>(Wz1, ws + WS_B, ws + WS_ACC);
        kmid<<<NB, 1024, 0, stream>>>(Az2, Bz1, ws);
        kz<<<NB, 512, 0, stream>>>(Wz2, ws + WS_B + 256 * 9 * HH, ws + WS_ACC);
        kout<<<NB, 512, 0, stream>>>(x, oWx, ob, oAx, oBx, obd,
                                     oWz, oAz, oBz, Bz2, ws, out);
    } else {
        lora_fused<<<NB, 1024, 0, stream>>>(
            x, Wx0, b0, Ax0, Bx0, bd0, Wx1, b1, Ax1, Bx1, bd1,
            Wx2, b2, Ax2, Bx2, bd2, Wz1, Az1, Bz1, Wz2, Az2, Bz2,
            oWx, ob, oAx, oBx, obd, oWz, oAz, oBz, out);
    }
}

// Round 4
// 79.843 us; speedup vs baseline: 1.4454x; 1.4454x over previous
//
#include <hip/hip_runtime.h>

#define NB    256
#define DIN   128
#define HH    512
#define RANK  8
#define SCALE 2.0f
#define LN2   0.69314718f
#define C192  5.2083335e-3f

// ---- workspace layout (float offsets) ----
#define WS_Z0   0
#define WS_P1   131072
#define WS_P2   262144
#define WS_END  393216

typedef float v2f __attribute__((ext_vector_type(2)));
typedef _Float16 h4v __attribute__((ext_vector_type(4)));

__device__ __forceinline__ v2f mk2(float a, float b) { v2f r; r.x = a; r.y = b; return r; }

// ---- packed fp32 VOP3P helpers (2 FMAs per instruction) ----
__device__ __forceinline__ v2f pk_fma(v2f a, v2f b, v2f c) {
    v2f d; asm("v_pk_fma_f32 %0, %1, %2, %3" : "=v"(d) : "v"(a), "v"(b), "v"(c)); return d;
}
__device__ __forceinline__ v2f pk_mul(v2f a, v2f b) {
    v2f d; asm("v_pk_mul_f32 %0, %1, %2" : "=v"(d) : "v"(a), "v"(b)); return d;
}
__device__ __forceinline__ v2f pk_fma_blo(v2f a, v2f b, v2f c) {
    v2f d; asm("v_pk_fma_f32 %0, %1, %2, %3 op_sel:[0,0,0] op_sel_hi:[1,0,1]"
               : "=v"(d) : "v"(a), "v"(b), "v"(c)); return d;
}
__device__ __forceinline__ v2f pk_fma_bhi(v2f a, v2f b, v2f c) {
    v2f d; asm("v_pk_fma_f32 %0, %1, %2, %3 op_sel:[0,1,0] op_sel_hi:[1,1,1]"
               : "=v"(d) : "v"(a), "v"(b), "v"(c)); return d;
}

__device__ __forceinline__ float sp_stable(float v) {
    float e = __expf(-fabsf(v));
    return fmaxf(v, 0.0f) + __logf(1.0f + e);
}
__device__ __forceinline__ float sp_poly(float v) {
    float u = v * v;
    float t = fmaf(u, -C192, 0.125f);
    t = fmaf(u, t, LN2);
    return fmaf(v, 0.5f, t);
}

#define DPP_ADD(x, ctrl, rm, bm, bc)                                            \
    (x) = (x) + __int_as_float(__builtin_amdgcn_update_dpp(                     \
              0, __float_as_int(x), (ctrl), (rm), (bm), (bc)))

__device__ __forceinline__ float wave_sum64(float x) {
    DPP_ADD(x, 0x111, 0xf, 0xf, true);
    DPP_ADD(x, 0x112, 0xf, 0xf, true);
    DPP_ADD(x, 0x114, 0xf, 0xf, true);
    DPP_ADD(x, 0x118, 0xf, 0xf, true);
    DPP_ADD(x, 0x142, 0xa, 0xf, false);
    DPP_ADD(x, 0x143, 0xc, 0xf, false);
    return x;
}

// ------------------------------------------------------------------
// kzstep: block = (sample-octet o, 64-row group g).
// mode 0: z0 = sp(xpre0) -> outv.
// mode 1: pre1 = xpre1 + sum_k z0_k*sp_poly(Wz1+D) -> outv (zin = z0 raw).
// mode 2: pre2 = xpre2 + sum_k sp(pre1)_k*sp_poly(Wz2+D) -> outv.
// Wz rows staged ONCE per block as fp16 LDS tile, shared by 8 samples:
// Wz L2 traffic drops 8x vs per-sample streaming.
// ------------------------------------------------------------------
__global__ __launch_bounds__(1024, 4) void kzstep(
    const float* __restrict__ x,
    const float* __restrict__ Wx, const float* __restrict__ bb,
    const float* __restrict__ Ax, const float* __restrict__ Bx,
    const float* __restrict__ bd,
    const float* __restrict__ Wz, const float* __restrict__ Az,
    const float* __restrict__ Bz,
    const float* __restrict__ zin, float* __restrict__ outv, const int mode)
{
    const int bid  = blockIdx.x;
    const int o    = bid >> 3;       // sample octet 0..31
    const int g    = bid & 7;        // row group 0..7 (64 rows)
    const int tid  = threadIdx.x;
    const int lane = tid & 63;
    const int wid  = tid >> 6;       // 0..15

    __shared__ float x_s[8][DIN + 4];            // +4 pad: kill 8-way bank alias
    __shared__ float tx_s[8][RANK];
    __shared__ float xpre_s[64][9];
    __shared__ float z_s[8][HH];
    __shared__ _Float16 Wt[64 * HH];             // fp16 Wz tile (64 KB)
    __shared__ float bz_s[8][64][RANK];
    __shared__ float red_s[4][8][2][65];         // [quad][s][khalf][row]

    const v2f cA2 = mk2(-C192, -C192);
    const v2f cB2 = mk2(0.125f, 0.125f);
    const v2f cL2 = mk2(LN2, LN2);
    const v2f cH2 = mk2(0.5f, 0.5f);

    // ---- stage x (8 samples) ----
    {
        const int s = tid >> 7, d = tid & 127;
        x_s[s][d] = x[(o * 8 + s) * DIN + d];
    }
    // ---- stage z / Wz-fp16 / bz (z-modes only) ----
    if (mode) {
        {   // z for 8 samples (apply sp for mode 2)
            const int s = tid >> 7, k4 = tid & 127;
            float4 zv = *reinterpret_cast<const float4*>(zin + ((size_t)(o * 8 + s)) * HH + k4 * 4);
            if (mode == 2) {
                zv.x = sp_stable(zv.x); zv.y = sp_stable(zv.y);
                zv.z = sp_stable(zv.z); zv.w = sp_stable(zv.w);
            }
            *reinterpret_cast<float4*>(&z_s[s][k4 * 4]) = zv;
        }
        {   // Wz rows -> fp16 tile (RNE via _Float16 cast)
            #pragma unroll
            for (int j = 0; j < 8; ++j) {
                const int fi  = tid + j * 1024;
                const int row = fi >> 7, c4 = fi & 127;
                float4 w = *reinterpret_cast<const float4*>(Wz + (g * 64 + row) * HH + c4 * 4);
                h4v hv;
                hv.x = (_Float16)w.x; hv.y = (_Float16)w.y;
                hv.z = (_Float16)w.z; hv.w = (_Float16)w.w;
                reinterpret_cast<h4v*>(Wt)[fi] = hv;
            }
        }
        {   // Bz rows for (8 samples x 64 rows)
            const int s = tid >> 7, t2 = tid & 127;
            const int rw = t2 >> 1, q = t2 & 1;
            *reinterpret_cast<float4*>(&bz_s[s][rw][q * 4]) =
                *reinterpret_cast<const float4*>(
                    Bz + ((size_t)(o * 8 + s) * HH + g * 64 + rw) * RANK + q * 4);
        }
    }
    __syncthreads();

    // ---- tx[s][r] = Ax[s,r,:] . x[s] (64 dots, 8 lanes each) ----
    if (tid < 512) {
        const int p = tid >> 3, l = tid & 7;
        const int s = p >> 3, r = p & 7;
        const float* Ab = Ax + ((size_t)(o * 8 + s) * RANK + r) * DIN;
        float acc = 0.f;
        #pragma unroll
        for (int j = 0; j < 16; ++j) { const int d = l + 8 * j; acc += Ab[d] * x_s[s][d]; }
        acc += __shfl_down(acc, 4, 8);
        acc += __shfl_down(acc, 2, 8);
        acc += __shfl_down(acc, 1, 8);
        if (l == 0) tx_s[s][r] = acc;
    }
    __syncthreads();

    // ---- xpre for (64 rows x 8 samples) ----
    if (tid < 512) {
        const int row = tid >> 3, s = tid & 7;
        const int h  = g * 64 + row;
        const int sb = o * 8 + s;
        const float4* wrow = reinterpret_cast<const float4*>(Wx + h * DIN);
        float acc = 0.f;
        #pragma unroll 8
        for (int q = 0; q < DIN / 4; ++q) {
            float4 w = wrow[q];
            const float* xs = &x_s[s][q * 4];
            acc += w.x * xs[0] + w.y * xs[1] + w.z * xs[2] + w.w * xs[3];
        }
        const float* bxr = Bx + ((size_t)sb * HH + h) * RANK;
        float t = 0.f;
        #pragma unroll
        for (int r = 0; r < RANK; ++r) t += bxr[r] * tx_s[s][r];
        const float v = acc + SCALE * t + bb[h] + bd[(size_t)sb * HH + h];
        if (mode == 0) outv[(size_t)sb * HH + h] = sp_stable(v);
        else           xpre_s[row][s] = v;
    }
    if (mode == 0) return;

    // ---- z-GEMV: wave (s, khalf) -> 64 rows x 256 k ----
    {
        const int s   = wid >> 1;
        const int khf = wid & 1;
        const int c0  = khf * 256 + (lane << 2);
        const int sb  = o * 8 + s;
        const bool odd = lane & 1;

        v2f zk2[2], az[RANK][2];
        {
            float4 zz = *reinterpret_cast<const float4*>(&z_s[s][c0]);
            zk2[0] = mk2(zz.x, zz.y); zk2[1] = mk2(zz.z, zz.w);
        }
        #pragma unroll
        for (int r = 0; r < RANK; ++r) {
            float4 a4 = *reinterpret_cast<const float4*>(Az + ((size_t)sb * RANK + r) * HH + c0);
            az[r][0] = mk2(SCALE * a4.x, SCALE * a4.y);
            az[r][1] = mk2(SCALE * a4.z, SCALE * a4.w);
        }

        const _Float16* wp = Wt + c0;
        v2f wA[2], wB[2], bzA[4], bzB[4];

        auto loadw = [&](v2f* dst, int row) {
            h4v hv = *reinterpret_cast<const h4v*>(wp + row * HH);
            dst[0] = mk2((float)hv.x, (float)hv.y);
            dst[1] = mk2((float)hv.z, (float)hv.w);
        };
        auto loadb = [&](v2f* dst, int row) {
            float4 q0 = *reinterpret_cast<const float4*>(&bz_s[s][row][0]);
            float4 q1 = *reinterpret_cast<const float4*>(&bz_s[s][row][4]);
            dst[0] = mk2(q0.x, q0.y); dst[1] = mk2(q0.z, q0.w);
            dst[2] = mk2(q1.x, q1.y); dst[3] = mk2(q1.z, q1.w);
        };
        auto rowsum = [&](const v2f* wz, const v2f* bz) -> float {
            v2f sv = mk2(0.f, 0.f);
            #pragma unroll
            for (int gg = 0; gg < 2; ++gg) {
                v2f d = wz[gg];
                d = pk_fma_blo(az[0][gg], bz[0], d);
                d = pk_fma_bhi(az[1][gg], bz[0], d);
                d = pk_fma_blo(az[2][gg], bz[1], d);
                d = pk_fma_bhi(az[3][gg], bz[1], d);
                d = pk_fma_blo(az[4][gg], bz[2], d);
                d = pk_fma_bhi(az[5][gg], bz[2], d);
                d = pk_fma_blo(az[6][gg], bz[3], d);
                d = pk_fma_bhi(az[7][gg], bz[3], d);
                v2f u = pk_mul(d, d);
                v2f t = pk_fma(u, cA2, cB2);
                t = pk_fma(u, t, cL2);
                t = pk_fma(d, cH2, t);
                sv = pk_fma(zk2[gg], t, sv);
            }
            return sv.x + sv.y;
        };

        loadw(wA, 0); loadb(bzA, 0);
        #pragma unroll 1
        for (int hs = 0; hs < 64; hs += 2) {
            loadw(wB, hs + 1); loadb(bzB, hs + 1);
            float sA = rowsum(wA, bzA);
            const int hn = (hs + 2) & 63;   // wrap keeps in-bounds; row 0 reload unused
            loadw(wA, hn); loadb(bzA, hn);
            float sB = rowsum(wB, bzB);

            float m  = odd ? sB : sA;
            float o2 = odd ? sA : sB;
            m = m + __int_as_float(__builtin_amdgcn_update_dpp(
                    0, __float_as_int(o2), 0xB1, 0xf, 0xf, true)); // quad_perm xor1
            DPP_ADD(m, 0x112, 0xf, 0xf, true);
            DPP_ADD(m, 0x114, 0xf, 0xf, true);
            DPP_ADD(m, 0x118, 0xf, 0xf, true);
            if ((lane & 14) == 14) red_s[lane >> 4][s][khf][hs + (lane & 1)] = m;
        }
    }
    __syncthreads();

    // ---- combine partials + xpre -> pre ----
    if (tid < 512) {
        const int row = tid >> 3, s = tid & 7;
        float acc = xpre_s[row][s];
        #pragma unroll
        for (int q = 0; q < 4; ++q)
            acc += red_s[q][s][0][row] + red_s[q][s][1][row];
        outv[((size_t)(o * 8 + s)) * HH + g * 64 + row] = acc;
    }
}

// ------------------------------------------------------------------
// kout: z2 = sp(pre2); output layer; reduce to out[b].
// ------------------------------------------------------------------
__global__ __launch_bounds__(512, 2) void kout(
    const float* __restrict__ x,
    const float* __restrict__ oWx, const float* __restrict__ ob,
    const float* __restrict__ oAx, const float* __restrict__ oBx, const float* __restrict__ obd,
    const float* __restrict__ oWz, const float* __restrict__ oAz, const float* __restrict__ oBz,
    const float* __restrict__ pre2, float* __restrict__ out)
{
    const int b = blockIdx.x, tid = threadIdx.x;
    __shared__ float x_s[DIN];
    __shared__ float red_s[HH];
    __shared__ float tx_s[RANK];

    if (tid < DIN) x_s[tid] = x[b * DIN + tid];
    __syncthreads();

    float partial;
    {
        const int h = tid;
        const float z2 = sp_stable(pre2[(size_t)b * HH + h]);
        float d = 0.f;
        #pragma unroll
        for (int r = 0; r < RANK; ++r)
            d = fmaf(oBz[b * RANK + r], oAz[((size_t)b * RANK + r) * HH + h], d);
        partial = z2 * sp_poly(fmaf(SCALE, d, oWz[h]));
        if (tid < DIN) partial += oWx[tid] * x_s[tid];
    }
    red_s[tid] = partial;
    __syncthreads();

    if (tid < 128) {
        const int r = tid >> 4, l = tid & 15;
        const float* Ab = oAx + ((size_t)b * RANK + r) * DIN;
        float s = 0.f;
        #pragma unroll
        for (int k = 0; k < 8; ++k) { int d = l + 16 * k; s += Ab[d] * x_s[d]; }
        s += __shfl_down(s, 8, 16);
        s += __shfl_down(s, 4, 16);
        s += __shfl_down(s, 2, 16);
        s += __shfl_down(s, 1, 16);
        if (l == 0) tx_s[r] = s;
    }
    __syncthreads();
    for (int st = 256; st > 0; st >>= 1) {
        if (tid < st) red_s[tid] += red_s[tid + st];
        __syncthreads();
    }
    if (tid == 0) {
        float t2 = 0.f;
        #pragma unroll
        for (int r = 0; r < RANK; ++r) t2 = fmaf(oBx[b * RANK + r], tx_s[r], t2);
        out[b] = red_s[0] + ob[0] + obd[b] + SCALE * t2;
    }
}

// ==================================================================
// Fallback single-kernel path (round-2 kernel) if ws too small.
// ==================================================================
__global__ __launch_bounds__(1024, 4) void lora_fused(
    const float* __restrict__ x,
    const float* __restrict__ Wx0, const float* __restrict__ b0,
    const float* __restrict__ Ax0, const float* __restrict__ Bx0, const float* __restrict__ bd0,
    const float* __restrict__ Wx1, const float* __restrict__ b1,
    const float* __restrict__ Ax1, const float* __restrict__ Bx1, const float* __restrict__ bd1,
    const float* __restrict__ Wx2, const float* __restrict__ b2,
    const float* __restrict__ Ax2, const float* __restrict__ Bx2, const float* __restrict__ bd2,
    const float* __restrict__ Wz1, const float* __restrict__ Az1, const float* __restrict__ Bz1,
    const float* __restrict__ Wz2, const float* __restrict__ Az2, const float* __restrict__ Bz2,
    const float* __restrict__ oWx, const float* __restrict__ ob,
    const float* __restrict__ oAx, const float* __restrict__ oBx, const float* __restrict__ obd,
    const float* __restrict__ oWz, const float* __restrict__ oAz, const float* __restrict__ oBz,
    float* __restrict__ out)
{
    const int b    = blockIdx.x;
    const int tid  = threadIdx.x;
    const int lane = tid & 63;
    const int wid  = tid >> 6;
    const int rg   = wid >> 1;
    const int ch   = wid & 1;
    const bool odd = lane & 1;

    __shared__ float x_s[DIN];
    __shared__ float z_s[HH];
    __shared__ float tx_s[4][RANK];
    __shared__ float xpre_s[3][HH];
    __shared__ float red4_s[4][2][HH + 2];
    __shared__ __attribute__((aligned(16))) float Az_s[2][RANK * HH];
    __shared__ __attribute__((aligned(16))) float Bz_s[2][HH * RANK];
    __shared__ float red8[16];

    const v2f cA2 = mk2(-C192, -C192);
    const v2f cB2 = mk2(0.125f, 0.125f);
    const v2f cL2 = mk2(LN2, LN2);
    const v2f cH2 = mk2(0.5f, 0.5f);

    if (tid < DIN) x_s[tid] = x[b * DIN + tid];
    {
        const float4* a1 = reinterpret_cast<const float4*>(Az1 + b * RANK * HH);
        const float4* a2 = reinterpret_cast<const float4*>(Az2 + b * RANK * HH);
        const float4* z1 = reinterpret_cast<const float4*>(Bz1 + b * HH * RANK);
        const float4* z2 = reinterpret_cast<const float4*>(Bz2 + b * HH * RANK);
        reinterpret_cast<float4*>(Az_s[0])[tid] = a1[tid];
        reinterpret_cast<float4*>(Az_s[1])[tid] = a2[tid];
        reinterpret_cast<float4*>(Bz_s[0])[tid] = z1[tid];
        reinterpret_cast<float4*>(Bz_s[1])[tid] = z2[tid];
    }
    __syncthreads();

    if (tid < 512) {
        const int g = tid >> 7;
        const int t = tid & 127;
        const int r = t >> 4, l = t & 15;
        const float* A  = (g == 0) ? Ax0 : (g == 1) ? Ax1 : (g == 2) ? Ax2 : oAx;
        const float* Ab = A + (b * RANK + r) * DIN;
        float s = 0.f;
        #pragma unroll
        for (int k = 0; k < 8; ++k) { int d = l + 16 * k; s += Ab[d] * x_s[d]; }
        s += __shfl_down(s, 8, 16);
        s += __shfl_down(s, 4, 16);
        s += __shfl_down(s, 2, 16);
        s += __shfl_down(s, 1, 16);
        if (l == 0) tx_s[g][r] = s;
    }
    __syncthreads();

    #pragma unroll 1
    for (int idx = tid; idx < 3 * HH; idx += 1024) {
        const int l = idx >> 9;
        const int h = idx & (HH - 1);
        const float* Wxl = (l == 0) ? Wx0 : (l == 1) ? Wx1 : Wx2;
        const float* bl  = (l == 0) ? b0  : (l == 1) ? b1  : b2;
        const float* Bxl = (l == 0) ? Bx0 : (l == 1) ? Bx1 : Bx2;
        const float* bdl = (l == 0) ? bd0 : (l == 1) ? bd1 : bd2;
        const float4* wrow = reinterpret_cast<const float4*>(Wxl + h * DIN);
        float s = 0.f;
        #pragma unroll 8
        for (int q = 0; q < DIN / 4; ++q) {
            float4 w = wrow[q];
            const float* xs = &x_s[q * 4];
            s += w.x * xs[0] + w.y * xs[1] + w.z * xs[2] + w.w * xs[3];
        }
        const float* bxr = Bxl + (b * HH + h) * RANK;
        float t = 0.f;
        #pragma unroll
        for (int r = 0; r < RANK; ++r) t += bxr[r] * tx_s[l][r];
        xpre_s[l][h] = s + SCALE * t + bl[h] + bdl[b * HH + h];
    }
    __syncthreads();

    if (tid < HH) z_s[tid] = sp_stable(xpre_s[0][tid]);
    __syncthreads();

    auto zlayer = [&](const float* __restrict__ Wz, int li) {
        const int c0 = ch * 256 + (lane << 2);
        v2f zk2[2], az[RANK][2];
        {
            float4 zz = *reinterpret_cast<const float4*>(&z_s[c0]);
            zk2[0] = mk2(zz.x, zz.y); zk2[1] = mk2(zz.z, zz.w);
        }
        #pragma unroll
        for (int r = 0; r < RANK; ++r) {
            float4 a4 = *reinterpret_cast<const float4*>(&Az_s[li][r * HH + c0]);
            az[r][0] = mk2(SCALE * a4.x, SCALE * a4.y);
            az[r][1] = mk2(SCALE * a4.z, SCALE * a4.w);
        }
        const float* wp = Wz + (rg * 64) * HH + c0;
        const float* bp = &Bz_s[li][(rg * 64) * RANK];
        float* rp = &red4_s[lane >> 4][ch][rg * 64 + (lane & 1)];

        v2f wA[2], wB[2], bzA[4], bzB[4];
        auto loadw = [&](v2f* dst, int row) {
            float4 w4 = *reinterpret_cast<const float4*>(wp + row * HH);
            dst[0] = mk2(w4.x, w4.y); dst[1] = mk2(w4.z, w4.w);
        };
        auto loadb = [&](v2f* dst, int row) {
            const float4* q = reinterpret_cast<const float4*>(bp + row * RANK);
            float4 q0 = q[0], q1 = q[1];
            dst[0] = mk2(q0.x, q0.y); dst[1] = mk2(q0.z, q0.w);
            dst[2] = mk2(q1.x, q1.y); dst[3] = mk2(q1.z, q1.w);
        };
        auto rowsum = [&](const v2f* wz, const v2f* bz) -> float {
            v2f s = mk2(0.f, 0.f);
            #pragma unroll
            for (int g = 0; g < 2; ++g) {
                v2f d = wz[g];
                d = pk_fma_blo(az[0][g], bz[0], d);
                d = pk_fma_bhi(az[1][g], bz[0], d);
                d = pk_fma_blo(az[2][g], bz[1], d);
                d = pk_fma_bhi(az[3][g], bz[1], d);
                d = pk_fma_blo(az[4][g], bz[2], d);
                d = pk_fma_bhi(az[5][g], bz[2], d);
                d = pk_fma_blo(az[6][g], bz[3], d);
                d = pk_fma_bhi(az[7][g], bz[3], d);
                v2f u = pk_mul(d, d);
                v2f t = pk_fma(u, cA2, cB2);
                t = pk_fma(u, t, cL2);
                t = pk_fma(d, cH2, t);
                s = pk_fma(zk2[g], t, s);
            }
            return s.x + s.y;
        };

        loadw(wA, 0); loadb(bzA, 0);
        #pragma unroll 1
        for (int hs = 0; hs < 64; hs += 2) {
            loadw(wB, hs + 1); loadb(bzB, hs + 1);
            float sA = rowsum(wA, bzA);
            const int hn = (hs + 2) & 63;
            loadw(wA, hn); loadb(bzA, hn);
            float sB = rowsum(wB, bzB);
            float m = odd ? sB : sA;
            float o = odd ? sA : sB;
            m = m + __int_as_float(__builtin_amdgcn_update_dpp(
                    0, __float_as_int(o), 0xB1, 0xf, 0xf, true));
            DPP_ADD(m, 0x112, 0xf, 0xf, true);
            DPP_ADD(m, 0x114, 0xf, 0xf, true);
            DPP_ADD(m, 0x118, 0xf, 0xf, true);
            if ((lane & 14) == 14) rp[hs] = m;
        }
    };

    zlayer(Wz1, 0);
    __syncthreads();
    if (tid < HH) {
        float acc = xpre_s[1][tid];
        #pragma unroll
        for (int q = 0; q < 4; ++q) acc += red4_s[q][0][tid] + red4_s[q][1][tid];
        z_s[tid] = sp_stable(acc);
    }
    __syncthreads();

    zlayer(Wz2, 1);
    __syncthreads();
    if (tid < HH) {
        float acc = xpre_s[2][tid];
        #pragma unroll
        for (int q = 0; q < 4; ++q) acc += red4_s[q][0][tid] + red4_s[q][1][tid];
        z_s[tid] = sp_stable(acc);
    }
    __syncthreads();

    {
        float partial = 0.f;
        if (tid < HH) {
            const float* oBzb = oBz + b * RANK;
            const float* oAzb = oAz + b * RANK * HH;
            float d = 0.f;
            #pragma unroll
            for (int r = 0; r < RANK; ++r) d = fmaf(oBzb[r], oAzb[r * HH + tid], d);
            partial = z_s[tid] * sp_poly(fmaf(SCALE, d, oWz[tid]));
            if (tid < DIN) partial += oWx[tid] * x_s[tid];
        }
        partial = wave_sum64(partial);
        if (lane == 63) red8[wid] = partial;
        __syncthreads();
        if (tid == 0) {
            float t = 0.f;
            #pragma unroll
            for (int w = 0; w < 8; ++w) t += red8[w];
            float t2 = 0.f;
            const float* oBxb = oBx + b * RANK;
            #pragma unroll
            for (int r = 0; r < RANK; ++r) t2 = fmaf(oBxb[r], tx_s[3][r], t2);
            out[b] = t + ob[0] + obd[b] + SCALE * t2;
        }
    }
}

extern "C" void kernel_launch(void* const* d_in, const int* in_sizes, int n_in,
                              void* d_out, int out_size, void* d_ws, size_t ws_size,
                              hipStream_t stream) {
    const float* x   = (const float*)d_in[0];
    const float* Wx0 = (const float*)d_in[1];
    const float* b0  = (const float*)d_in[2];
    const float* Ax0 = (const float*)d_in[3];
    const float* Bx0 = (const float*)d_in[4];
    const float* bd0 = (const float*)d_in[5];
    const float* Wx1 = (const float*)d_in[6];
    const float* b1  = (const float*)d_in[7];
    const float* Ax1 = (const float*)d_in[8];
    const float* Bx1 = (const float*)d_in[9];
    const float* bd1 = (const float*)d_in[10];
    const float* Wx2 = (const float*)d_in[11];
    const float* b2  = (const float*)d_in[12];
    const float* Ax2 = (const float*)d_in[13];
    const float* Bx2 = (const float*)d_in[14];
    const float* bd2 = (const float*)d_in[15];
    const float* Wz1 = (const float*)d_in[16];
    const float* Az1 = (const float*)d_in[17];
    const float* Bz1 = (const float*)d_in[18];
    const float* Wz2 = (const float*)d_in[19];
    const float* Az2 = (const float*)d_in[20];
    const float* Bz2 = (const float*)d_in[21];
    const float* oWx = (const float*)d_in[22];
    const float* ob  = (const float*)d_in[23];
    const float* oAx = (const float*)d_in[24];
    const float* oBx = (const float*)d_in[25];
    const float* obd = (const float*)d_in[26];
    const float* oWz = (const float*)d_in[27];
    const float* oAz = (const float*)d_in[28];
    const float* oBz = (const float*)d_in[29];
    float* out = (float*)d_out;

    if (ws_size >= (size_t)WS_END * sizeof(float) && d_ws != nullptr) {
        float* ws = (float*)d_ws;
        kzstep<<<NB, 1024, 0, stream>>>(x, Wx0, b0, Ax0, Bx0, bd0,
                                        nullptr, nullptr, nullptr,
                                        nullptr, ws + WS_Z0, 0);
        kzstep<<<NB, 1024, 0, stream>>>(x, Wx1, b1, Ax1, Bx1, bd1,
                                        Wz1, Az1, Bz1,
                                        ws + WS_Z0, ws + WS_P1, 1);
        kzstep<<<NB, 1024, 0, stream>>>(x, Wx2, b2, Ax2, Bx2, bd2,
                                        Wz2, Az2, Bz2,
                                        ws + WS_P1, ws + WS_P2, 2);
        kout<<<NB, 512, 0, stream>>>(x, oWx, ob, oAx, oBx, obd,
                                     oWz, oAz, oBz, ws + WS_P2, out);
    } else {
        lora_fused<<<NB, 1024, 0, stream>>>(
            x, Wx0, b0, Ax0, Bx0, bd0, Wx1, b1, Ax1, Bx1, bd1,
            Wx2, b2, Ax2, Bx2, bd2, Wz1, Az1, Bz1, Wz2, Az2, Bz2,
            oWx, ob, oAx, oBx, obd, oWz, oAz, oBz, out);
    }
}

// Round 5
// 76.292 us; speedup vs baseline: 1.5127x; 1.0465x over previous
//
#include <hip/hip_runtime.h>

#define NB    256
#define DIN   128
#define HH    512
#define RANK  8
#define SCALE 2.0f
#define LN2   0.69314718f
#define C192  5.2083335e-3f

typedef float v2f __attribute__((ext_vector_type(2)));

__device__ __forceinline__ v2f mk2(float a, float b) { v2f r; r.x = a; r.y = b; return r; }

// ---- packed fp32 VOP3P helpers (2 FMAs per instruction) ----
__device__ __forceinline__ v2f pk_fma(v2f a, v2f b, v2f c) {
    v2f d; asm("v_pk_fma_f32 %0, %1, %2, %3" : "=v"(d) : "v"(a), "v"(b), "v"(c)); return d;
}
__device__ __forceinline__ v2f pk_mul(v2f a, v2f b) {
    v2f d; asm("v_pk_mul_f32 %0, %1, %2" : "=v"(d) : "v"(a), "v"(b)); return d;
}
// broadcast b.lo to both halves
__device__ __forceinline__ v2f pk_fma_blo(v2f a, v2f b, v2f c) {
    v2f d; asm("v_pk_fma_f32 %0, %1, %2, %3 op_sel:[0,0,0] op_sel_hi:[1,0,1]"
               : "=v"(d) : "v"(a), "v"(b), "v"(c)); return d;
}
// broadcast b.hi to both halves
__device__ __forceinline__ v2f pk_fma_bhi(v2f a, v2f b, v2f c) {
    v2f d; asm("v_pk_fma_f32 %0, %1, %2, %3 op_sel:[0,1,0] op_sel_hi:[1,1,1]"
               : "=v"(d) : "v"(a), "v"(b), "v"(c)); return d;
}

__device__ __forceinline__ float sp_stable(float v) {
    float e = __expf(-fabsf(v));
    return fmaxf(v, 0.0f) + __logf(1.0f + e);
}
__device__ __forceinline__ float sp_poly(float v) {
    float u = v * v;
    float t = fmaf(u, -C192, 0.125f);
    t = fmaf(u, t, LN2);
    return fmaf(v, 0.5f, t);
}

#define DPP_ADD(x, ctrl, rm, bm, bc)                                            \
    (x) = (x) + __int_as_float(__builtin_amdgcn_update_dpp(                     \
              0, __float_as_int(x), (ctrl), (rm), (bm), (bc)))

__device__ __forceinline__ float wave_sum64(float x) {
    DPP_ADD(x, 0x111, 0xf, 0xf, true);
    DPP_ADD(x, 0x112, 0xf, 0xf, true);
    DPP_ADD(x, 0x114, 0xf, 0xf, true);
    DPP_ADD(x, 0x118, 0xf, 0xf, true);
    DPP_ADD(x, 0x142, 0xa, 0xf, false);
    DPP_ADD(x, 0x143, 0xc, 0xf, false);
    return x;
}

__global__ __launch_bounds__(1024, 4) void lora_fused(
    const float* __restrict__ x,
    const float* __restrict__ Wx0, const float* __restrict__ b0,
    const float* __restrict__ Ax0, const float* __restrict__ Bx0, const float* __restrict__ bd0,
    const float* __restrict__ Wx1, const float* __restrict__ b1,
    const float* __restrict__ Ax1, const float* __restrict__ Bx1, const float* __restrict__ bd1,
    const float* __restrict__ Wx2, const float* __restrict__ b2,
    const float* __restrict__ Ax2, const float* __restrict__ Bx2, const float* __restrict__ bd2,
    const float* __restrict__ Wz1, const float* __restrict__ Az1, const float* __restrict__ Bz1,
    const float* __restrict__ Wz2, const float* __restrict__ Az2, const float* __restrict__ Bz2,
    const float* __restrict__ oWx, const float* __restrict__ ob,
    const float* __restrict__ oAx, const float* __restrict__ oBx, const float* __restrict__ obd,
    const float* __restrict__ oWz, const float* __restrict__ oAz, const float* __restrict__ oBz,
    float* __restrict__ out)
{
    const int b    = blockIdx.x;
    const int tid  = threadIdx.x;
    const int lane = tid & 63;
    const int wid  = tid >> 6;     // 0..15
    const int rg   = wid >> 1;     // row group   0..7 (64 rows each)
    const int ch   = wid & 1;      // column half 0..1 (256 cols each)
    const bool odd = lane & 1;

    __shared__ float x_s[DIN];
    __shared__ float z_s[HH];
    __shared__ float tx_s[4][RANK];            // per-layer Ax@x (0,1,2,out)
    __shared__ float xpre_s[3][HH];            // hoisted x-path pre-activations
    __shared__ float red4_s[4][2][HH + 2];     // [16-lane-quadrant][col-half][row]
    __shared__ __attribute__((aligned(16))) float Az_s[2][RANK * HH];
    __shared__ __attribute__((aligned(16))) float Bz_s[2][HH * RANK];
    __shared__ float red8[16];

    // packed sp_poly constants
    const v2f cA2 = mk2(-C192, -C192);
    const v2f cB2 = mk2(0.125f, 0.125f);
    const v2f cL2 = mk2(LN2, LN2);
    const v2f cH2 = mk2(0.5f, 0.5f);

    // ---- prologue: stage x + all per-sample z-LoRA factors into LDS ----
    if (tid < DIN) x_s[tid] = x[b * DIN + tid];
    {
        const float4* a1 = reinterpret_cast<const float4*>(Az1 + b * RANK * HH);
        const float4* a2 = reinterpret_cast<const float4*>(Az2 + b * RANK * HH);
        const float4* z1 = reinterpret_cast<const float4*>(Bz1 + b * HH * RANK);
        const float4* z2 = reinterpret_cast<const float4*>(Bz2 + b * HH * RANK);
        reinterpret_cast<float4*>(Az_s[0])[tid] = a1[tid];
        reinterpret_cast<float4*>(Az_s[1])[tid] = a2[tid];
        reinterpret_cast<float4*>(Bz_s[0])[tid] = z1[tid];
        reinterpret_cast<float4*>(Bz_s[1])[tid] = z2[tid];
    }
    __syncthreads();

    // ---- tx for all 4 layers in parallel: tx_s[g][r] = sum_d A_g[b,r,d]*x[d]
    if (tid < 512) {
        const int g = tid >> 7;            // layer: 0,1,2,3(out) — wave-uniform
        const int t = tid & 127;
        const int r = t >> 4, l = t & 15;
        const float* A  = (g == 0) ? Ax0 : (g == 1) ? Ax1 : (g == 2) ? Ax2 : oAx;
        const float* Ab = A + (b * RANK + r) * DIN;
        float s = 0.f;
        #pragma unroll
        for (int k = 0; k < 8; ++k) { int d = l + 16 * k; s += Ab[d] * x_s[d]; }
        s += __shfl_down(s, 8, 16);
        s += __shfl_down(s, 4, 16);
        s += __shfl_down(s, 2, 16);
        s += __shfl_down(s, 1, 16);
        if (l == 0) tx_s[g][r] = s;
    }
    __syncthreads();

    // ---- all 3 layers' x-path pre-activations, fully parallel (1536 rows) ----
    #pragma unroll 1
    for (int idx = tid; idx < 3 * HH; idx += 1024) {
        const int l = idx >> 9;            // wave-uniform (512-row chunks)
        const int h = idx & (HH - 1);
        const float* Wxl = (l == 0) ? Wx0 : (l == 1) ? Wx1 : Wx2;
        const float* bl  = (l == 0) ? b0  : (l == 1) ? b1  : b2;
        const float* Bxl = (l == 0) ? Bx0 : (l == 1) ? Bx1 : Bx2;
        const float* bdl = (l == 0) ? bd0 : (l == 1) ? bd1 : bd2;
        const float4* wrow = reinterpret_cast<const float4*>(Wxl + h * DIN);
        float s = 0.f;
        #pragma unroll 8
        for (int q = 0; q < DIN / 4; ++q) {
            float4 w = wrow[q];
            const float* xs = &x_s[q * 4];
            s += w.x * xs[0] + w.y * xs[1] + w.z * xs[2] + w.w * xs[3];
        }
        const float* bxr = Bxl + (b * HH + h) * RANK;
        float t = 0.f;
        #pragma unroll
        for (int r = 0; r < RANK; ++r) t += bxr[r] * tx_s[l][r];
        xpre_s[l][h] = s + SCALE * t + bl[h] + bdl[b * HH + h];
    }
    __syncthreads();

    // ---- layer 0 ----
    if (tid < HH) z_s[tid] = sp_stable(xpre_s[0][tid]);
    __syncthreads();

    // Wave-cooperative z-path: wave owns 64 rows x 256 cols (4 consecutive cols/lane).
    // Wz stream: 8-deep register pipeline (8 dwordx4 in flight per wave) to cover
    // L2/HBM latency; statically-indexed circular buffer via 8x-unrolled inner loop.
    auto zlayer = [&](const float* __restrict__ Wz, int li) {
        const int c0 = ch * 256 + (lane << 2);
        v2f zk2[2], az[RANK][2];
        {
            float4 zz = *reinterpret_cast<const float4*>(&z_s[c0]);
            zk2[0] = mk2(zz.x, zz.y); zk2[1] = mk2(zz.z, zz.w);
        }
        #pragma unroll
        for (int r = 0; r < RANK; ++r) {
            float4 a4 = *reinterpret_cast<const float4*>(&Az_s[li][r * HH + c0]);
            az[r][0] = mk2(SCALE * a4.x, SCALE * a4.y);
            az[r][1] = mk2(SCALE * a4.z, SCALE * a4.w);
        }

        const float* wp = Wz + (rg * 64) * HH + c0;
        const float* bp = &Bz_s[li][(rg * 64) * RANK];
        float* rp = &red4_s[lane >> 4][ch][rg * 64 + (lane & 1)];

        // prologue: fill 8-row register pipeline
        v2f wbuf[8][2];
        #pragma unroll
        for (int j = 0; j < 8; ++j) {
            float4 w4 = *reinterpret_cast<const float4*>(wp + j * HH);
            wbuf[j][0] = mk2(w4.x, w4.y); wbuf[j][1] = mk2(w4.z, w4.w);
        }

        float sEven = 0.f;
        #pragma unroll 1
        for (int hs8 = 0; hs8 < 64; hs8 += 8) {
            #pragma unroll
            for (int j = 0; j < 8; ++j) {
                const int row = hs8 + j;
                // bz from LDS (uniform address -> broadcast)
                const float4* q = reinterpret_cast<const float4*>(bp + row * RANK);
                float4 q0 = q[0], q1 = q[1];
                v2f bz0 = mk2(q0.x, q0.y), bz1 = mk2(q0.z, q0.w);
                v2f bz2 = mk2(q1.x, q1.y), bz3 = mk2(q1.z, q1.w);

                v2f sv = mk2(0.f, 0.f);
                #pragma unroll
                for (int gg = 0; gg < 2; ++gg) {
                    v2f d = wbuf[j][gg];
                    d = pk_fma_blo(az[0][gg], bz0, d);
                    d = pk_fma_bhi(az[1][gg], bz0, d);
                    d = pk_fma_blo(az[2][gg], bz1, d);
                    d = pk_fma_bhi(az[3][gg], bz1, d);
                    d = pk_fma_blo(az[4][gg], bz2, d);
                    d = pk_fma_bhi(az[5][gg], bz2, d);
                    d = pk_fma_blo(az[6][gg], bz3, d);
                    d = pk_fma_bhi(az[7][gg], bz3, d);
                    v2f u = pk_mul(d, d);
                    v2f t = pk_fma(u, cA2, cB2);
                    t = pk_fma(u, t, cL2);
                    t = pk_fma(d, cH2, t);      // sp_poly(d), packed
                    sv = pk_fma(zk2[gg], t, sv);
                }
                float s = sv.x + sv.y;

                // refill slot j with row+8 (wrap keeps in-bounds; wrapped rows unused)
                {
                    float4 w4 = *reinterpret_cast<const float4*>(wp + ((row + 8) & 63) * HH);
                    wbuf[j][0] = mk2(w4.x, w4.y); wbuf[j][1] = mk2(w4.z, w4.w);
                }

                if (j & 1) {
                    // merged 2-row reduce: even row on even lanes, odd row on odd lanes
                    float m = odd ? s : sEven;
                    float o = odd ? sEven : s;
                    m = m + __int_as_float(__builtin_amdgcn_update_dpp(
                            0, __float_as_int(o), 0xB1, 0xf, 0xf, true)); // quad_perm xor1
                    DPP_ADD(m, 0x112, 0xf, 0xf, true);   // row_shr:2 (parity-preserving)
                    DPP_ADD(m, 0x114, 0xf, 0xf, true);   // row_shr:4
                    DPP_ADD(m, 0x118, 0xf, 0xf, true);   // row_shr:8
                    if ((lane & 14) == 14) rp[row - 1] = m;
                } else {
                    sEven = s;
                }
            }
        }
    };

    // ---- layer 1 ----
    zlayer(Wz1, 0);
    __syncthreads();
    if (tid < HH) {
        float acc = xpre_s[1][tid];
        #pragma unroll
        for (int q = 0; q < 4; ++q) acc += red4_s[q][0][tid] + red4_s[q][1][tid];
        z_s[tid] = sp_stable(acc);
    }
    __syncthreads();

    // ---- layer 2 ----
    zlayer(Wz2, 1);
    __syncthreads();
    if (tid < HH) {
        float acc = xpre_s[2][tid];
        #pragma unroll
        for (int q = 0; q < 4; ++q) acc += red4_s[q][0][tid] + red4_s[q][1][tid];
        z_s[tid] = sp_stable(acc);
    }
    __syncthreads();

    // ---- output layer ----
    {
        float partial = 0.f;
        if (tid < HH) {
            const float* oBzb = oBz + b * RANK;
            const float* oAzb = oAz + b * RANK * HH;
            float d = 0.f;
            #pragma unroll
            for (int r = 0; r < RANK; ++r) d = fmaf(oBzb[r], oAzb[r * HH + tid], d);
            partial = z_s[tid] * sp_poly(fmaf(SCALE, d, oWz[tid]));
            if (tid < DIN) partial += oWx[tid] * x_s[tid];
        }
        partial = wave_sum64(partial);
        if (lane == 63) red8[wid] = partial;
        __syncthreads();
        if (tid == 0) {
            float t = 0.f;
            #pragma unroll
            for (int w = 0; w < 8; ++w) t += red8[w];
            float t2 = 0.f;
            const float* oBxb = oBx + b * RANK;
            #pragma unroll
            for (int r = 0; r < RANK; ++r) t2 = fmaf(oBxb[r], tx_s[3][r], t2);
            out[b] = t + ob[0] + obd[b] + SCALE * t2;
        }
    }
}

extern "C" void kernel_launch(void* const* d_in, const int* in_sizes, int n_in,
                              void* d_out, int out_size, void* d_ws, size_t ws_size,
                              hipStream_t stream) {
    const float* x   = (const float*)d_in[0];
    const float* Wx0 = (const float*)d_in[1];
    const float* b0  = (const float*)d_in[2];
    const float* Ax0 = (const float*)d_in[3];
    const float* Bx0 = (const float*)d_in[4];
    const float* bd0 = (const float*)d_in[5];
    const float* Wx1 = (const float*)d_in[6];
    const float* b1  = (const float*)d_in[7];
    const float* Ax1 = (const float*)d_in[8];
    const float* Bx1 = (const float*)d_in[9];
    const float* bd1 = (const float*)d_in[10];
    const float* Wx2 = (const float*)d_in[11];
    const float* b2  = (const float*)d_in[12];
    const float* Ax2 = (const float*)d_in[13];
    const float* Bx2 = (const float*)d_in[14];
    const float* bd2 = (const float*)d_in[15];
    const float* Wz1 = (const float*)d_in[16];
    const float* Az1 = (const float*)d_in[17];
    const float* Bz1 = (const float*)d_in[18];
    const float* Wz2 = (const float*)d_in[19];
    const float* Az2 = (const float*)d_in[20];
    const float* Bz2 = (const float*)d_in[21];
    const float* oWx = (const float*)d_in[22];
    const float* ob  = (const float*)d_in[23];
    const float* oAx = (const float*)d_in[24];
    const float* oBx = (const float*)d_in[25];
    const float* obd = (const float*)d_in[26];
    const float* oWz = (const float*)d_in[27];
    const float* oAz = (const float*)d_in[28];
    const float* oBz = (const float*)d_in[29];
    float* out = (float*)d_out;

    lora_fused<<<NB, 1024, 0, stream>>>(
        x, Wx0, b0, Ax0, Bx0, bd0, Wx1, b1, Ax1, Bx1, bd1,
        Wx2, b2, Ax2, Bx2, bd2, Wz1, Az1, Bz1, Wz2, Az2, Bz2,
        oWx, ob, oAx, oBx, obd, oWz, oAz, oBz, out);
}